// Round 22
// baseline (1351.396 us; speedup 1.0000x reference)
//
#include <hip/hip_runtime.h>
#include <hip/hip_bf16.h>

typedef __attribute__((ext_vector_type(8))) short short8;
typedef __attribute__((ext_vector_type(4))) float floatx4;
typedef __hip_bfloat16 bf16_t;

#define DD 768

__device__ __forceinline__ float sigmoid_f(float x) { return 1.f / (1.f + __expf(-x)); }

__device__ __forceinline__ void gl2lds16(const void* g, void* l) {
  __builtin_amdgcn_global_load_lds((const __attribute__((address_space(1))) void*)g,
                                   (__attribute__((address_space(3))) void*)l, 16, 0, 0);
}

// ---------------------------------------------------------------------------
// 256x256-tile, BK=64, 512-thread (8 waves = 2M x 4N) bf16 GEMM — R8/R11/R15
// validated pipeline. A double-buffered (4-phase lead), B TRIPLE-buffered
// (6-phase lead >= HBM latency). LDS = 160 KiB. Ledger (R8-verified):
//   p0: wait vmcnt(6) [last tile: 2]; barrier; read av0,bv0; stage A0(t+1)
//   p1: no wait; read bv1; stage A1(t+1)
//   p2: wait vmcnt(8) [last tile: 0]; barrier; read av1; stage B0(t+2)
//   p3: register-only MFMA; stage B1(t+2)
// R22 epilogue: NT stores kept (R20: preserves L3 for weights across replays,
// -38 us on the rest) staged through LDS (reused post-K-loop), emitted as
// coalesced NT 16B stores via ext_vector floatx4 (R21's HIP float4 is a
// struct -> builtin rejects it; floatx4 is a clang vector -> accepted).
// R20's scalar NT stores caused partial-line write amplification
// (WRITE 256->329 MB); full 128B lines fix that.
// ---------------------------------------------------------------------------
__global__ __launch_bounds__(512, 2) void gemm256(
    const bf16_t* __restrict__ A, int lda, int M,
    const bf16_t* __restrict__ Wt, int Kdim,
    int nRowT, int nColT,
    const float* __restrict__ bias,
    float* __restrict__ out, int N)
{
  __shared__ __attribute__((aligned(16))) unsigned char lds[163840];
  const int tid = threadIdx.x;
  const int wave = tid >> 6, lane = tid & 63;
  const int l15 = lane & 15, kq = lane >> 4;
  const int wm = wave >> 2, wn = wave & 3;

  const int nwg = gridDim.x;
  const int q8 = nwg >> 3, r8 = nwg & 7;
  const int xcd = blockIdx.x & 7, lin = blockIdx.x >> 3;
  const int wgid = (xcd < r8 ? xcd * (q8 + 1) : r8 * (q8 + 1) + (xcd - r8) * q8) + lin;
  const int rowt = wgid % nRowT, colt = wgid / nRowT;
  const int rowbase = rowt * 256, colbase = colt * 256;

  floatx4 acc[8][4] = {};
  const int nkt = Kdim >> 6;

  auto stageA = [&](int mh, int kt, int buf) {
    const int kbase = kt << 6;
    #pragma unroll
    for (int rr = 0; rr < 2; ++rr) {
      const int L = rr * 64 + wave * 8;
      const int lrow_base = (L >> 6) * 128 + mh * 64 + (L & 63);
      const int lrow = lrow_base + (lane >> 3);
      const int slotp = (lane & 7) ^ (lrow & 7);
      const int gr = min(rowbase + lrow, M - 1);
      gl2lds16(A + (size_t)gr * lda + kbase + slotp * 8,
               lds + buf * 32768 + lrow_base * 128);
    }
  };
  auto stageB = [&](int nh, int kt, int buf) {
    const int kbase = kt << 6;
    #pragma unroll
    for (int rr = 0; rr < 2; ++rr) {
      const int L = rr * 64 + wave * 8;
      const int lrow_base = (L >> 5) * 64 + nh * 32 + (L & 31);
      const int lrow = lrow_base + (lane >> 3);
      const int slotp = (lane & 7) ^ (lrow & 7);
      const int gn = colbase + lrow;
      gl2lds16(Wt + (size_t)gn * Kdim + kbase + slotp * 8,
               lds + 65536 + buf * 32768 + lrow_base * 128);
    }
  };

#define READ_A(av_, mh_) \
  _Pragma("unroll") for (int i = 0; i < 4; ++i) { \
    const int r_ = wm * 128 + (mh_) * 64 + i * 16 + l15; \
    _Pragma("unroll") for (int s = 0; s < 2; ++s) { \
      const int sl_ = (s * 4 + kq) ^ (r_ & 7); \
      av_[i][s] = *reinterpret_cast<const short8*>(Ab + r_ * 128 + sl_ * 16); } }

#define READ_B(bv_, nh_) \
  _Pragma("unroll") for (int j = 0; j < 2; ++j) { \
    const int r_ = wn * 64 + (nh_) * 32 + j * 16 + l15; \
    _Pragma("unroll") for (int s = 0; s < 2; ++s) { \
      const int sl_ = (s * 4 + kq) ^ (r_ & 7); \
      bv_[j][s] = *reinterpret_cast<const short8*>(Bb + r_ * 128 + sl_ * 16); } }

#define MFMA_Q(av_, bv_, mb_, nb_) \
  __builtin_amdgcn_s_setprio(1); \
  _Pragma("unroll") for (int i = 0; i < 4; ++i) \
    _Pragma("unroll") for (int j = 0; j < 2; ++j) \
      _Pragma("unroll") for (int s = 0; s < 2; ++s) \
        acc[(mb_) + i][(nb_) + j] = __builtin_amdgcn_mfma_f32_16x16x32_bf16( \
            av_[i][s], bv_[j][s], acc[(mb_) + i][(nb_) + j], 0, 0, 0); \
  __builtin_amdgcn_s_setprio(0);

  stageB(0, 0, 0); stageB(1, 0, 0);
  stageA(0, 0, 0); stageA(1, 0, 0);
  if (nkt > 1) { stageB(0, 1, 1); stageB(1, 1, 1); }

  short8 av0[4][2], av1[4][2], bv0[2][2], bv1[2][2];
  int curA = 0, curB = 0;
  for (int t = 0; t < nkt; ++t) {
    const bool hasA = (t + 1 < nkt), hasB = (t + 2 < nkt);
    const unsigned char* Ab = lds + curA * 32768;
    const unsigned char* Bb = lds + 65536 + curB * 32768;
    int tgtB = curB + 2; if (tgtB >= 3) tgtB -= 3;

    if (hasA) { asm volatile("s_waitcnt vmcnt(6)" ::: "memory"); }
    else      { asm volatile("s_waitcnt vmcnt(2)" ::: "memory"); }
    __builtin_amdgcn_s_barrier();
    READ_A(av0, 0)
    READ_B(bv0, 0)
    if (hasA) stageA(0, t + 1, curA ^ 1);
    MFMA_Q(av0, bv0, 0, 0)

    READ_B(bv1, 1)
    if (hasA) stageA(1, t + 1, curA ^ 1);
    MFMA_Q(av0, bv1, 0, 2)

    if (hasA) { asm volatile("s_waitcnt vmcnt(8)" ::: "memory"); }
    else      { asm volatile("s_waitcnt vmcnt(0)" ::: "memory"); }
    __builtin_amdgcn_s_barrier();
    READ_A(av1, 1)
    if (hasB) stageB(0, t + 2, tgtB);
    MFMA_Q(av1, bv0, 4, 0)

    if (hasB) stageB(1, t + 2, tgtB);
    MFMA_Q(av1, bv1, 4, 2)

    curA ^= 1; curB = (curB + 1 == 3) ? 0 : curB + 1;
  }
#undef READ_A
#undef READ_B
#undef MFMA_Q

  // epilogue: stage acc into LDS (reused; pitch 260 -> 2-way max), then
  // coalesced NT floatx4 stores (full 128B lines, no write amplification).
  // Two halves of 128 rows: 128 x 260 fp32 = 130 KB <= 160 KB.
  {
    float* ldsF = (float*)lds;
    const int hi = lane >> 4;
    __builtin_amdgcn_s_barrier();   // all waves done with K-loop LDS reads
    #pragma unroll
    for (int h = 0; h < 2; ++h) {
      if (wm == h) {                // wave-uniform branch
        #pragma unroll
        for (int i = 0; i < 8; ++i)
          #pragma unroll
          for (int j = 0; j < 4; ++j) {
            const int c = wn * 64 + j * 16 + l15;
            const float bb = bias[colbase + c];
            #pragma unroll
            for (int rg = 0; rg < 4; ++rg) {
              const int rl = i * 16 + hi * 4 + rg;
              ldsF[rl * 260 + c] = acc[i][j][rg] + bb;
            }
          }
      }
      asm volatile("s_waitcnt lgkmcnt(0)" ::: "memory");
      __builtin_amdgcn_s_barrier();
      {
        const int row = tid >> 2, q = tid & 3;
        const int r = rowbase + h * 128 + row;
        if (r < M) {
          const size_t obase = (size_t)r * N + colbase + q * 64;
          #pragma unroll
          for (int k = 0; k < 16; ++k) {
            floatx4 v = *reinterpret_cast<const floatx4*>(&ldsF[row * 260 + q * 64 + k * 4]);
            __builtin_nontemporal_store(v, reinterpret_cast<floatx4*>(out + obase + k * 4));
          }
        }
      }
      if (h == 0) __builtin_amdgcn_s_barrier();   // reads done before half-1 writes
    }
  }
}

// ---------------------------------------------------------------------------
// 128x128-tile, BK=64, 256-thread (4 waves, 64x64/wave) bf16 GEMM, 64 KB LDS
// double-buffer -> 2 blocks/CU (R9/R11/R15-validated). Per-768-chunk row
// shifts. gate_other is bf16 (h already round-trips bf16 as the A operand).
// ---------------------------------------------------------------------------
__global__ __launch_bounds__(256, 2) void gemm128(
    const bf16_t* __restrict__ A, int lda, int M, int nRowT,
    int s0, int s1, int s2,
    const bf16_t* __restrict__ Wt, int Kdim,
    const float* __restrict__ bias,
    float* __restrict__ out, int N,
    bf16_t* __restrict__ out_bf,
    const bf16_t* __restrict__ gate_other)
{
  __shared__ __attribute__((aligned(16))) unsigned char lds[65536];
  const int tid = threadIdx.x;
  const int wave = tid >> 6, lane = tid & 63;
  const int l15 = lane & 15, kq = lane >> 4;
  const int wm = wave >> 1, wn = wave & 1;

  const int nwg = gridDim.x;
  const int q8 = nwg >> 3, r8 = nwg & 7;
  const int xcd = blockIdx.x & 7, lin = blockIdx.x >> 3;
  const int wgid = (xcd < r8 ? xcd * (q8 + 1) : r8 * (q8 + 1) + (xcd - r8) * q8) + lin;
  const int rowt = wgid % nRowT, colt = wgid / nRowT;
  const int rowbase = rowt * 128, colbase = colt * 128;

  floatx4 acc[4][4] = {};
  const int nkt = Kdim >> 6;

  auto stage = [&](int kt, int buf) {
    const int kbase = kt << 6;
    const int chunk = kbase / 768;
    const int shift = (chunk == 0) ? s0 : ((chunk == 1) ? s1 : s2);
    const int csrc  = kbase - chunk * 768;
    #pragma unroll
    for (int q = 0; q < 4; ++q) {
      const int Lb  = q * 32 + wave * 8;
      const int row = Lb + (lane >> 3);
      const int slotp = (lane & 7) ^ (row & 7);
      const int gr = min(rowbase + row, M - 1) + shift;
      gl2lds16(A + (size_t)gr * lda + csrc + slotp * 8,
               lds + buf * 16384 + Lb * 128);
      const int gn = colbase + row;
      gl2lds16(Wt + (size_t)gn * Kdim + kbase + slotp * 8,
               lds + 32768 + buf * 16384 + Lb * 128);
    }
  };

  stage(0, 0);
  int cur = 0;
  for (int t = 0; t < nkt; ++t) {
    if (t + 1 < nkt) {
      stage(t + 1, cur ^ 1);
      asm volatile("s_waitcnt vmcnt(8)" ::: "memory");
    } else {
      asm volatile("s_waitcnt vmcnt(0)" ::: "memory");
    }
    __builtin_amdgcn_s_barrier();

    const unsigned char* Ab = lds + cur * 16384;
    const unsigned char* Bb = lds + 32768 + cur * 16384;
    short8 av[4][2], bv[4][2];
    #pragma unroll
    for (int i = 0; i < 4; ++i) {
      const int r = wm * 64 + i * 16 + l15;
      #pragma unroll
      for (int s = 0; s < 2; ++s) {
        const int sl = (s * 4 + kq) ^ (r & 7);
        av[i][s] = *reinterpret_cast<const short8*>(Ab + r * 128 + sl * 16);
      }
    }
    #pragma unroll
    for (int j = 0; j < 4; ++j) {
      const int r = wn * 64 + j * 16 + l15;
      #pragma unroll
      for (int s = 0; s < 2; ++s) {
        const int sl = (s * 4 + kq) ^ (r & 7);
        bv[j][s] = *reinterpret_cast<const short8*>(Bb + r * 128 + sl * 16);
      }
    }
    __builtin_amdgcn_s_setprio(1);
    #pragma unroll
    for (int i = 0; i < 4; ++i)
      #pragma unroll
      for (int j = 0; j < 4; ++j)
        #pragma unroll
        for (int s = 0; s < 2; ++s)
          acc[i][j] = __builtin_amdgcn_mfma_f32_16x16x32_bf16(
              av[i][s], bv[j][s], acc[i][j], 0, 0, 0);
    __builtin_amdgcn_s_setprio(0);
    asm volatile("s_waitcnt lgkmcnt(0)" ::: "memory");
    __builtin_amdgcn_s_barrier();
    cur ^= 1;
  }

  const int hi = lane >> 4;
  #pragma unroll
  for (int i = 0; i < 4; ++i)
    #pragma unroll
    for (int j = 0; j < 4; ++j) {
      const int c = colbase + wn * 64 + j * 16 + l15;
      const float bb = bias[c];
      #pragma unroll
      for (int rg = 0; rg < 4; ++rg) {
        const int r = rowbase + wm * 64 + i * 16 + hi * 4 + rg;
        if (r < M) {
          float v = acc[i][j][rg] + bb;
          if (gate_other)
            v = __bfloat162float(gate_other[(size_t)r * N + c]) * sigmoid_f(v);
          if (out)    out[(size_t)r * N + c] = v;
          if (out_bf) out_bf[(size_t)r * N + c] = __float2bfloat16(v);
        }
      }
    }
}

// out[n][k] bf16 = in[k][n] fp32. 64x64 tile, float4 loads / ushort4 stores.
// Dims must be multiples of 64. Block 256 threads.
// GRID: dim3(nDim/64, kDim/64) where kDim is the INPUT's row count (fan_in).
__global__ void transpose_cvt2(const float* __restrict__ in, bf16_t* __restrict__ out,
                               int in_ld, int out_ld)
{
  __shared__ float tile[64][65];
  const int k0 = blockIdx.y * 64, n0 = blockIdx.x * 64;
  const int tid = threadIdx.x;
  const int rw = tid >> 4, c4 = tid & 15;     // 16 rows/pass, float4 col
  #pragma unroll
  for (int p = 0; p < 4; ++p) {
    const int row = p * 16 + rw;
    const float4 v = *reinterpret_cast<const float4*>(
        in + (size_t)(k0 + row) * in_ld + n0 + c4 * 4);
    tile[row][c4 * 4 + 0] = v.x;
    tile[row][c4 * 4 + 1] = v.y;
    tile[row][c4 * 4 + 2] = v.z;
    tile[row][c4 * 4 + 3] = v.w;
  }
  __syncthreads();
  #pragma unroll
  for (int p = 0; p < 4; ++p) {
    const int nrow = p * 16 + rw;
    const int k = c4 * 4;
    ushort4 w;
    w.x = __bfloat16_as_ushort(__float2bfloat16(tile[k + 0][nrow]));
    w.y = __bfloat16_as_ushort(__float2bfloat16(tile[k + 1][nrow]));
    w.z = __bfloat16_as_ushort(__float2bfloat16(tile[k + 2][nrow]));
    w.w = __bfloat16_as_ushort(__float2bfloat16(tile[k + 3][nrow]));
    *reinterpret_cast<ushort4*>(out + (size_t)(n0 + nrow) * out_ld + k0 + k) = w;
  }
}

__global__ void build_wct(const float* __restrict__ cw, bf16_t* __restrict__ wct) {
  const int idx = blockIdx.x * 256 + threadIdx.x;
  const int o = idx / 2304, c = idx - o * 2304;
  const int k = c / 768, i = c - k * 768;
  wct[idx] = __float2bfloat16(cw[o * 2304 + i * 3 + k]);
}

__global__ void build_bias(const float* __restrict__ bmv, const float* __restrict__ bmg,
                           const float* __restrict__ brg, const float* __restrict__ bhw,
                           float* __restrict__ out) {
  const int i = blockIdx.x * 256 + threadIdx.x;
  float v;
  if (i < 768) v = bmv[i];
  else if (i < 1536) v = bmg[i - 768];
  else if (i < 2304) v = brg[i - 1536];
  else v = bhw[i - 2304];
  out[i] = v;
}

__global__ void embed_k(const int* __restrict__ x, const float* __restrict__ emb,
                        const float* __restrict__ pos, bf16_t* __restrict__ hpad) {
  const int t = blockIdx.x, tid = threadIdx.x;
  int id = 0, tt = t - 2;
  if (t >= 2) id = x[tt];
  #pragma unroll
  for (int q = 0; q < 3; ++q) {
    const int d = tid + q * 256;
    float v = 0.f;
    if (t >= 2) v = emb[(size_t)id * DD + d] + pos[(size_t)tt * DD + d];
    hpad[(size_t)t * DD + d] = __float2bfloat16(v);
  }
}

// one block per output row t. bf16-only state: left/right read from curOldB.
// tmp is bf16 [2048][3072]: [val|gate|rg|hw], bias already added in GEMM.
__global__ __launch_bounds__(256) void merge_ew(
    const bf16_t* __restrict__ curOldB,
    bf16_t* __restrict__ curNewB,
    const bf16_t* __restrict__ tmp,
    const float* __restrict__ rmsw, int step)
{
  const int t = blockIdx.x, tid = threadIdx.x;
  if (t < step) {  // passthrough rows (bf16 row = 1536 B = 96 uint4)
    const uint4* sB = (const uint4*)(curOldB + (size_t)t * DD);
    uint4* dB = (uint4*)(curNewB + (size_t)t * DD);
    if (tid < 96) dB[tid] = sB[tid];
    return;
  }
  const int r = t - step;
  const bf16_t* row = tmp + (size_t)r * 3072;
  float mv[3]; float ss = 0.f;
  #pragma unroll
  for (int q = 0; q < 3; ++q) {
    const int d = tid + q * 256;
    const float m = __bfloat162float(row[d]) * sigmoid_f(__bfloat162float(row[768 + d]));
    mv[q] = m; ss += m * m;
  }
  #pragma unroll
  for (int o = 32; o >= 1; o >>= 1) ss += __shfl_down(ss, o, 64);
  __shared__ float red[4];
  if ((tid & 63) == 0) red[tid >> 6] = ss;
  __syncthreads();
  const float tot = red[0] + red[1] + red[2] + red[3];
  const float scale = rsqrtf(tot * (1.f / 768.f) + 1.1920929e-07f);
  #pragma unroll
  for (int q = 0; q < 3; ++q) {
    const int d = tid + q * 256;
    float merged = mv[q] * scale * rmsw[d];
    const float right = __bfloat162float(curOldB[(size_t)t * DD + d]);
    const float left  = __bfloat162float(curOldB[(size_t)r * DD + d]);
    const float hg = sigmoid_f(__bfloat162float(row[2304 + d]));
    merged = hg * merged + (1.f - hg) * right;
    const float rg = sigmoid_f(__bfloat162float(row[1536 + d]));
    merged = rg * merged + (1.f - rg) * (left + right) * 0.5f;
    curNewB[(size_t)t * DD + d] = __float2bfloat16(merged);
  }
}

extern "C" void kernel_launch(void* const* d_in, const int* in_sizes, int n_in,
                              void* d_out, int out_size, void* d_ws, size_t ws_size,
                              hipStream_t stream) {
  const int*   x      = (const int*)  d_in[0];
  const float* emb    = (const float*)d_in[1];
  const float* pos    = (const float*)d_in[2];
  const float* conv_w = (const float*)d_in[3];
  const float* conv_b = (const float*)d_in[4];
  const float* wg1    = (const float*)d_in[5];
  const float* bg1    = (const float*)d_in[6];
  const float* wmv    = (const float*)d_in[7];
  const float* bmv    = (const float*)d_in[8];
  const float* wmg    = (const float*)d_in[9];
  const float* bmg    = (const float*)d_in[10];
  const float* wrg    = (const float*)d_in[11];
  const float* brg    = (const float*)d_in[12];
  const float* whw    = (const float*)d_in[13];
  const float* bhw    = (const float*)d_in[14];
  const float* rmsw   = (const float*)d_in[15];
  const float* wpred  = (const float*)d_in[16];
  const float* bpred  = (const float*)d_in[17];

  char* ws = (char*)d_ws;
  size_t off = 0;
  auto carve = [&](size_t bytes) { char* p = ws + off; off += (bytes + 255) & ~(size_t)255; return p; };
  bf16_t* wpred_t  = (bf16_t*)carve(32000ull * 768 * 2);
  bf16_t* Wbig_t   = (bf16_t*)carve(3072ull * 1536 * 2);
  bf16_t* wc_t     = (bf16_t*)carve(768ull * 2304 * 2);
  bf16_t* wg1_t    = (bf16_t*)carve(768ull * 768 * 2);
  float*  bias_big = (float*) carve(3072 * 4);
  bf16_t* h_pad    = (bf16_t*)carve(2050ull * 768 * 2);
  bf16_t* hconv_bf = (bf16_t*)carve(2048ull * 768 * 2);
  bf16_t* currA_b  = (bf16_t*)carve(2048ull * 768 * 2);
  bf16_t* currB_b  = (bf16_t*)carve(2048ull * 768 * 2);
  bf16_t* tmp_bf   = (bf16_t*)carve(2048ull * 3072 * 2);

  hipMemsetAsync(Wbig_t + 2304ull * 1536, 0, 768ull * 1536 * 2, stream);
  // transposes: 64x64-tile vectorized. GRID = (n/64, fan_in/64).
  // wmv/wmg/wrg have fan_in = 1536 (comb = [left|right]) -> k-grid 24.
  transpose_cvt2<<<dim3(12, 24), 256, 0, stream>>>(wmv, Wbig_t,                        768, 1536);
  transpose_cvt2<<<dim3(12, 24), 256, 0, stream>>>(wmg, Wbig_t + 768ull * 1536,        768, 1536);
  transpose_cvt2<<<dim3(12, 24), 256, 0, stream>>>(wrg, Wbig_t + 1536ull * 1536,       768, 1536);
  transpose_cvt2<<<dim3(12, 12), 256, 0, stream>>>(whw, Wbig_t + 2304ull * 1536 + 768, 768, 1536);
  transpose_cvt2<<<dim3(12, 12), 256, 0, stream>>>(wg1, wg1_t, 768, 768);
  transpose_cvt2<<<dim3(500, 12), 256, 0, stream>>>(wpred, wpred_t, 32000, 768);
  build_wct<<<6912, 256, 0, stream>>>(conv_w, wc_t);
  build_bias<<<12, 256, 0, stream>>>(bmv, bmg, brg, bhw, bias_big);

  embed_k<<<2050, 256, 0, stream>>>(x, emb, pos, h_pad);

  // causal conv as shifted GEMM (K=2304, chunk shifts 0,1,2 into h_pad)
  gemm128<<<16 * 6, 256, 0, stream>>>(h_pad, 768, 2048, 16, 0, 1, 2,
                                      wc_t, 2304, conv_b, nullptr, 768, hconv_bf, nullptr);
  // curr0 = hconv * sigmoid(hconv @ wg1 + bg1)  (bf16-only state)
  gemm128<<<16 * 6, 256, 0, stream>>>(hconv_bf, 768, 2048, 16, 0, 0, 0,
                                      wg1_t, 768, bg1, nullptr, 768, currA_b, hconv_bf);

  bf16_t* curB = currA_b;
  bf16_t* nxtB = currB_b;
  for (int step = 1; step < 2048; step <<= 1) {
    const int M = 2048 - step;
    const int nRowT = (M + 127) / 128;
    // unified K=1536: chunk 0 = left (shift 0), chunk 1 = right (shift step)
    gemm128<<<nRowT * 24, 256, 0, stream>>>(
        curB, 768, M, nRowT, 0, step, 0, Wbig_t, 1536, bias_big,
        nullptr, 3072, tmp_bf, nullptr);
    merge_ew<<<2048, 256, 0, stream>>>(curB, nxtB, tmp_bf, rmsw, step);
    { bf16_t* tb_ = curB; curB = nxtB; nxtB = tb_; }
  }

  // logits = curr @ wpred + bpred  (NT floatx4 coalesced epilogue)
  gemm256<<<8 * 125, 512, 0, stream>>>(curB, 768, 2048, wpred_t, 768, 8, 125,
                                       bpred, (float*)d_out, 32000);
}

// Round 23
// 653.332 us; speedup vs baseline: 2.0685x; 2.0685x over previous
//
#include <hip/hip_runtime.h>
#include <hip/hip_bf16.h>

typedef __attribute__((ext_vector_type(8))) short short8;
typedef __attribute__((ext_vector_type(4))) float floatx4;
typedef __hip_bfloat16 bf16_t;

#define DD 768

__device__ __forceinline__ float sigmoid_f(float x) { return 1.f / (1.f + __expf(-x)); }

__device__ __forceinline__ void gl2lds16(const void* g, void* l) {
  __builtin_amdgcn_global_load_lds((const __attribute__((address_space(1))) void*)g,
                                   (__attribute__((address_space(3))) void*)l, 16, 0, 0);
}

// ---------------------------------------------------------------------------
// 256x256-tile, BK=64, 512-thread (8 waves = 2M x 4N) bf16 GEMM — R8/R11/R15
// validated pipeline. A double-buffered (4-phase lead), B TRIPLE-buffered
// (6-phase lead >= HBM latency). LDS = 160 KiB. Ledger (R8-verified):
//   p0: wait vmcnt(6) [last tile: 2]; barrier; read av0,bv0; stage A0(t+1)
//   p1: no wait; read bv1; stage A1(t+1)
//   p2: wait vmcnt(8) [last tile: 0]; barrier; read av1; stage B0(t+2)
//   p3: register-only MFMA; stage B1(t+2)
// R23 epilogue: NT stores via LDS staging. COALESCING IS PER-INSTRUCTION
// WAVE FOOTPRINT (R22 lesson: 64 lanes @ 256B stride -> 3.2x write
// amplification). Layout: 8-lane groups write o8*16B + k*128B of ONE row
// -> every store instruction = one full aligned 128B line. LDS reads:
// 8 lanes cover 32 consecutive words (all 32 banks), row stride 260 words
// -> ~2-way (free).
// ---------------------------------------------------------------------------
__global__ __launch_bounds__(512, 2) void gemm256(
    const bf16_t* __restrict__ A, int lda, int M,
    const bf16_t* __restrict__ Wt, int Kdim,
    int nRowT, int nColT,
    const float* __restrict__ bias,
    float* __restrict__ out, int N)
{
  __shared__ __attribute__((aligned(16))) unsigned char lds[163840];
  const int tid = threadIdx.x;
  const int wave = tid >> 6, lane = tid & 63;
  const int l15 = lane & 15, kq = lane >> 4;
  const int wm = wave >> 2, wn = wave & 3;

  const int nwg = gridDim.x;
  const int q8 = nwg >> 3, r8 = nwg & 7;
  const int xcd = blockIdx.x & 7, lin = blockIdx.x >> 3;
  const int wgid = (xcd < r8 ? xcd * (q8 + 1) : r8 * (q8 + 1) + (xcd - r8) * q8) + lin;
  const int rowt = wgid % nRowT, colt = wgid / nRowT;
  const int rowbase = rowt * 256, colbase = colt * 256;

  floatx4 acc[8][4] = {};
  const int nkt = Kdim >> 6;

  auto stageA = [&](int mh, int kt, int buf) {
    const int kbase = kt << 6;
    #pragma unroll
    for (int rr = 0; rr < 2; ++rr) {
      const int L = rr * 64 + wave * 8;
      const int lrow_base = (L >> 6) * 128 + mh * 64 + (L & 63);
      const int lrow = lrow_base + (lane >> 3);
      const int slotp = (lane & 7) ^ (lrow & 7);
      const int gr = min(rowbase + lrow, M - 1);
      gl2lds16(A + (size_t)gr * lda + kbase + slotp * 8,
               lds + buf * 32768 + lrow_base * 128);
    }
  };
  auto stageB = [&](int nh, int kt, int buf) {
    const int kbase = kt << 6;
    #pragma unroll
    for (int rr = 0; rr < 2; ++rr) {
      const int L = rr * 64 + wave * 8;
      const int lrow_base = (L >> 5) * 64 + nh * 32 + (L & 31);
      const int lrow = lrow_base + (lane >> 3);
      const int slotp = (lane & 7) ^ (lrow & 7);
      const int gn = colbase + lrow;
      gl2lds16(Wt + (size_t)gn * Kdim + kbase + slotp * 8,
               lds + 65536 + buf * 32768 + lrow_base * 128);
    }
  };

#define READ_A(av_, mh_) \
  _Pragma("unroll") for (int i = 0; i < 4; ++i) { \
    const int r_ = wm * 128 + (mh_) * 64 + i * 16 + l15; \
    _Pragma("unroll") for (int s = 0; s < 2; ++s) { \
      const int sl_ = (s * 4 + kq) ^ (r_ & 7); \
      av_[i][s] = *reinterpret_cast<const short8*>(Ab + r_ * 128 + sl_ * 16); } }

#define READ_B(bv_, nh_) \
  _Pragma("unroll") for (int j = 0; j < 2; ++j) { \
    const int r_ = wn * 64 + (nh_) * 32 + j * 16 + l15; \
    _Pragma("unroll") for (int s = 0; s < 2; ++s) { \
      const int sl_ = (s * 4 + kq) ^ (r_ & 7); \
      bv_[j][s] = *reinterpret_cast<const short8*>(Bb + r_ * 128 + sl_ * 16); } }

#define MFMA_Q(av_, bv_, mb_, nb_) \
  __builtin_amdgcn_s_setprio(1); \
  _Pragma("unroll") for (int i = 0; i < 4; ++i) \
    _Pragma("unroll") for (int j = 0; j < 2; ++j) \
      _Pragma("unroll") for (int s = 0; s < 2; ++s) \
        acc[(mb_) + i][(nb_) + j] = __builtin_amdgcn_mfma_f32_16x16x32_bf16( \
            av_[i][s], bv_[j][s], acc[(mb_) + i][(nb_) + j], 0, 0, 0); \
  __builtin_amdgcn_s_setprio(0);

  stageB(0, 0, 0); stageB(1, 0, 0);
  stageA(0, 0, 0); stageA(1, 0, 0);
  if (nkt > 1) { stageB(0, 1, 1); stageB(1, 1, 1); }

  short8 av0[4][2], av1[4][2], bv0[2][2], bv1[2][2];
  int curA = 0, curB = 0;
  for (int t = 0; t < nkt; ++t) {
    const bool hasA = (t + 1 < nkt), hasB = (t + 2 < nkt);
    const unsigned char* Ab = lds + curA * 32768;
    const unsigned char* Bb = lds + 65536 + curB * 32768;
    int tgtB = curB + 2; if (tgtB >= 3) tgtB -= 3;

    if (hasA) { asm volatile("s_waitcnt vmcnt(6)" ::: "memory"); }
    else      { asm volatile("s_waitcnt vmcnt(2)" ::: "memory"); }
    __builtin_amdgcn_s_barrier();
    READ_A(av0, 0)
    READ_B(bv0, 0)
    if (hasA) stageA(0, t + 1, curA ^ 1);
    MFMA_Q(av0, bv0, 0, 0)

    READ_B(bv1, 1)
    if (hasA) stageA(1, t + 1, curA ^ 1);
    MFMA_Q(av0, bv1, 0, 2)

    if (hasA) { asm volatile("s_waitcnt vmcnt(8)" ::: "memory"); }
    else      { asm volatile("s_waitcnt vmcnt(0)" ::: "memory"); }
    __builtin_amdgcn_s_barrier();
    READ_A(av1, 1)
    if (hasB) stageB(0, t + 2, tgtB);
    MFMA_Q(av1, bv0, 4, 0)

    if (hasB) stageB(1, t + 2, tgtB);
    MFMA_Q(av1, bv1, 4, 2)

    curA ^= 1; curB = (curB + 1 == 3) ? 0 : curB + 1;
  }
#undef READ_A
#undef READ_B
#undef MFMA_Q

  // epilogue: stage acc into LDS (pitch 260), NT stores with full-line
  // per-instruction wave footprint: 8 lanes x 16B = one 128B line per row.
  {
    float* ldsF = (float*)lds;
    const int hi = lane >> 4;
    const int erow = tid >> 3, o8 = tid & 7;   // 64 rows/pass, 8 lanes/row
    __builtin_amdgcn_s_barrier();   // all waves done with K-loop LDS reads
    #pragma unroll
    for (int h = 0; h < 2; ++h) {
      if (wm == h) {                // wave-uniform branch
        #pragma unroll
        for (int i = 0; i < 8; ++i)
          #pragma unroll
          for (int j = 0; j < 4; ++j) {
            const int c = wn * 64 + j * 16 + l15;
            const float bb = bias[colbase + c];
            #pragma unroll
            for (int rg = 0; rg < 4; ++rg) {
              const int rl = i * 16 + hi * 4 + rg;
              ldsF[rl * 260 + c] = acc[i][j][rg] + bb;
            }
          }
      }
      asm volatile("s_waitcnt lgkmcnt(0)" ::: "memory");
      __builtin_amdgcn_s_barrier();
      #pragma unroll
      for (int p2 = 0; p2 < 2; ++p2) {
        const int rl = p2 * 64 + erow;
        const int r = rowbase + h * 128 + rl;
        if (r < M) {
          const size_t ob = (size_t)r * N + colbase + o8 * 4;
          #pragma unroll
          for (int k = 0; k < 8; ++k) {
            floatx4 v = *reinterpret_cast<const floatx4*>(&ldsF[rl * 260 + o8 * 4 + k * 32]);
            __builtin_nontemporal_store(v, reinterpret_cast<floatx4*>(out + ob + k * 32));
          }
        }
      }
      if (h == 0) __builtin_amdgcn_s_barrier();   // reads done before half-1 writes
    }
  }
}

// ---------------------------------------------------------------------------
// 128x128-tile, BK=64, 256-thread (4 waves, 64x64/wave) bf16 GEMM, 64 KB LDS
// double-buffer -> 2 blocks/CU (R9/R11/R15-validated). Per-768-chunk row
// shifts. gate_other is bf16 (h already round-trips bf16 as the A operand).
// ---------------------------------------------------------------------------
__global__ __launch_bounds__(256, 2) void gemm128(
    const bf16_t* __restrict__ A, int lda, int M, int nRowT,
    int s0, int s1, int s2,
    const bf16_t* __restrict__ Wt, int Kdim,
    const float* __restrict__ bias,
    float* __restrict__ out, int N,
    bf16_t* __restrict__ out_bf,
    const bf16_t* __restrict__ gate_other)
{
  __shared__ __attribute__((aligned(16))) unsigned char lds[65536];
  const int tid = threadIdx.x;
  const int wave = tid >> 6, lane = tid & 63;
  const int l15 = lane & 15, kq = lane >> 4;
  const int wm = wave >> 1, wn = wave & 1;

  const int nwg = gridDim.x;
  const int q8 = nwg >> 3, r8 = nwg & 7;
  const int xcd = blockIdx.x & 7, lin = blockIdx.x >> 3;
  const int wgid = (xcd < r8 ? xcd * (q8 + 1) : r8 * (q8 + 1) + (xcd - r8) * q8) + lin;
  const int rowt = wgid % nRowT, colt = wgid / nRowT;
  const int rowbase = rowt * 128, colbase = colt * 128;

  floatx4 acc[4][4] = {};
  const int nkt = Kdim >> 6;

  auto stage = [&](int kt, int buf) {
    const int kbase = kt << 6;
    const int chunk = kbase / 768;
    const int shift = (chunk == 0) ? s0 : ((chunk == 1) ? s1 : s2);
    const int csrc  = kbase - chunk * 768;
    #pragma unroll
    for (int q = 0; q < 4; ++q) {
      const int Lb  = q * 32 + wave * 8;
      const int row = Lb + (lane >> 3);
      const int slotp = (lane & 7) ^ (row & 7);
      const int gr = min(rowbase + row, M - 1) + shift;
      gl2lds16(A + (size_t)gr * lda + csrc + slotp * 8,
               lds + buf * 16384 + Lb * 128);
      const int gn = colbase + row;
      gl2lds16(Wt + (size_t)gn * Kdim + kbase + slotp * 8,
               lds + 32768 + buf * 16384 + Lb * 128);
    }
  };

  stage(0, 0);
  int cur = 0;
  for (int t = 0; t < nkt; ++t) {
    if (t + 1 < nkt) {
      stage(t + 1, cur ^ 1);
      asm volatile("s_waitcnt vmcnt(8)" ::: "memory");
    } else {
      asm volatile("s_waitcnt vmcnt(0)" ::: "memory");
    }
    __builtin_amdgcn_s_barrier();

    const unsigned char* Ab = lds + cur * 16384;
    const unsigned char* Bb = lds + 32768 + cur * 16384;
    short8 av[4][2], bv[4][2];
    #pragma unroll
    for (int i = 0; i < 4; ++i) {
      const int r = wm * 64 + i * 16 + l15;
      #pragma unroll
      for (int s = 0; s < 2; ++s) {
        const int sl = (s * 4 + kq) ^ (r & 7);
        av[i][s] = *reinterpret_cast<const short8*>(Ab + r * 128 + sl * 16);
      }
    }
    #pragma unroll
    for (int j = 0; j < 4; ++j) {
      const int r = wn * 64 + j * 16 + l15;
      #pragma unroll
      for (int s = 0; s < 2; ++s) {
        const int sl = (s * 4 + kq) ^ (r & 7);
        bv[j][s] = *reinterpret_cast<const short8*>(Bb + r * 128 + sl * 16);
      }
    }
    __builtin_amdgcn_s_setprio(1);
    #pragma unroll
    for (int i = 0; i < 4; ++i)
      #pragma unroll
      for (int j = 0; j < 4; ++j)
        #pragma unroll
        for (int s = 0; s < 2; ++s)
          acc[i][j] = __builtin_amdgcn_mfma_f32_16x16x32_bf16(
              av[i][s], bv[j][s], acc[i][j], 0, 0, 0);
    __builtin_amdgcn_s_setprio(0);
    asm volatile("s_waitcnt lgkmcnt(0)" ::: "memory");
    __builtin_amdgcn_s_barrier();
    cur ^= 1;
  }

  const int hi = lane >> 4;
  #pragma unroll
  for (int i = 0; i < 4; ++i)
    #pragma unroll
    for (int j = 0; j < 4; ++j) {
      const int c = colbase + wn * 64 + j * 16 + l15;
      const float bb = bias[c];
      #pragma unroll
      for (int rg = 0; rg < 4; ++rg) {
        const int r = rowbase + wm * 64 + i * 16 + hi * 4 + rg;
        if (r < M) {
          float v = acc[i][j][rg] + bb;
          if (gate_other)
            v = __bfloat162float(gate_other[(size_t)r * N + c]) * sigmoid_f(v);
          if (out)    out[(size_t)r * N + c] = v;
          if (out_bf) out_bf[(size_t)r * N + c] = __float2bfloat16(v);
        }
      }
    }
}

// out[n][k] bf16 = in[k][n] fp32. 64x64 tile, float4 loads / ushort4 stores.
// Dims must be multiples of 64. Block 256 threads.
// GRID: dim3(nDim/64, kDim/64) where kDim is the INPUT's row count (fan_in).
__global__ void transpose_cvt2(const float* __restrict__ in, bf16_t* __restrict__ out,
                               int in_ld, int out_ld)
{
  __shared__ float tile[64][65];
  const int k0 = blockIdx.y * 64, n0 = blockIdx.x * 64;
  const int tid = threadIdx.x;
  const int rw = tid >> 4, c4 = tid & 15;     // 16 rows/pass, float4 col
  #pragma unroll
  for (int p = 0; p < 4; ++p) {
    const int row = p * 16 + rw;
    const float4 v = *reinterpret_cast<const float4*>(
        in + (size_t)(k0 + row) * in_ld + n0 + c4 * 4);
    tile[row][c4 * 4 + 0] = v.x;
    tile[row][c4 * 4 + 1] = v.y;
    tile[row][c4 * 4 + 2] = v.z;
    tile[row][c4 * 4 + 3] = v.w;
  }
  __syncthreads();
  #pragma unroll
  for (int p = 0; p < 4; ++p) {
    const int nrow = p * 16 + rw;
    const int k = c4 * 4;
    ushort4 w;
    w.x = __bfloat16_as_ushort(__float2bfloat16(tile[k + 0][nrow]));
    w.y = __bfloat16_as_ushort(__float2bfloat16(tile[k + 1][nrow]));
    w.z = __bfloat16_as_ushort(__float2bfloat16(tile[k + 2][nrow]));
    w.w = __bfloat16_as_ushort(__float2bfloat16(tile[k + 3][nrow]));
    *reinterpret_cast<ushort4*>(out + (size_t)(n0 + nrow) * out_ld + k0 + k) = w;
  }
}

__global__ void build_wct(const float* __restrict__ cw, bf16_t* __restrict__ wct) {
  const int idx = blockIdx.x * 256 + threadIdx.x;
  const int o = idx / 2304, c = idx - o * 2304;
  const int k = c / 768, i = c - k * 768;
  wct[idx] = __float2bfloat16(cw[o * 2304 + i * 3 + k]);
}

__global__ void build_bias(const float* __restrict__ bmv, const float* __restrict__ bmg,
                           const float* __restrict__ brg, const float* __restrict__ bhw,
                           float* __restrict__ out) {
  const int i = blockIdx.x * 256 + threadIdx.x;
  float v;
  if (i < 768) v = bmv[i];
  else if (i < 1536) v = bmg[i - 768];
  else if (i < 2304) v = brg[i - 1536];
  else v = bhw[i - 2304];
  out[i] = v;
}

__global__ void embed_k(const int* __restrict__ x, const float* __restrict__ emb,
                        const float* __restrict__ pos, bf16_t* __restrict__ hpad) {
  const int t = blockIdx.x, tid = threadIdx.x;
  int id = 0, tt = t - 2;
  if (t >= 2) id = x[tt];
  #pragma unroll
  for (int q = 0; q < 3; ++q) {
    const int d = tid + q * 256;
    float v = 0.f;
    if (t >= 2) v = emb[(size_t)id * DD + d] + pos[(size_t)tt * DD + d];
    hpad[(size_t)t * DD + d] = __float2bfloat16(v);
  }
}

// one block per output row t. bf16-only state: left/right read from curOldB.
// tmp is bf16 [2048][3072]: [val|gate|rg|hw], bias already added in GEMM.
__global__ __launch_bounds__(256) void merge_ew(
    const bf16_t* __restrict__ curOldB,
    bf16_t* __restrict__ curNewB,
    const bf16_t* __restrict__ tmp,
    const float* __restrict__ rmsw, int step)
{
  const int t = blockIdx.x, tid = threadIdx.x;
  if (t < step) {  // passthrough rows (bf16 row = 1536 B = 96 uint4)
    const uint4* sB = (const uint4*)(curOldB + (size_t)t * DD);
    uint4* dB = (uint4*)(curNewB + (size_t)t * DD);
    if (tid < 96) dB[tid] = sB[tid];
    return;
  }
  const int r = t - step;
  const bf16_t* row = tmp + (size_t)r * 3072;
  float mv[3]; float ss = 0.f;
  #pragma unroll
  for (int q = 0; q < 3; ++q) {
    const int d = tid + q * 256;
    const float m = __bfloat162float(row[d]) * sigmoid_f(__bfloat162float(row[768 + d]));
    mv[q] = m; ss += m * m;
  }
  #pragma unroll
  for (int o = 32; o >= 1; o >>= 1) ss += __shfl_down(ss, o, 64);
  __shared__ float red[4];
  if ((tid & 63) == 0) red[tid >> 6] = ss;
  __syncthreads();
  const float tot = red[0] + red[1] + red[2] + red[3];
  const float scale = rsqrtf(tot * (1.f / 768.f) + 1.1920929e-07f);
  #pragma unroll
  for (int q = 0; q < 3; ++q) {
    const int d = tid + q * 256;
    float merged = mv[q] * scale * rmsw[d];
    const float right = __bfloat162float(curOldB[(size_t)t * DD + d]);
    const float left  = __bfloat162float(curOldB[(size_t)r * DD + d]);
    const float hg = sigmoid_f(__bfloat162float(row[2304 + d]));
    merged = hg * merged + (1.f - hg) * right;
    const float rg = sigmoid_f(__bfloat162float(row[1536 + d]));
    merged = rg * merged + (1.f - rg) * (left + right) * 0.5f;
    curNewB[(size_t)t * DD + d] = __float2bfloat16(merged);
  }
}

extern "C" void kernel_launch(void* const* d_in, const int* in_sizes, int n_in,
                              void* d_out, int out_size, void* d_ws, size_t ws_size,
                              hipStream_t stream) {
  const int*   x      = (const int*)  d_in[0];
  const float* emb    = (const float*)d_in[1];
  const float* pos    = (const float*)d_in[2];
  const float* conv_w = (const float*)d_in[3];
  const float* conv_b = (const float*)d_in[4];
  const float* wg1    = (const float*)d_in[5];
  const float* bg1    = (const float*)d_in[6];
  const float* wmv    = (const float*)d_in[7];
  const float* bmv    = (const float*)d_in[8];
  const float* wmg    = (const float*)d_in[9];
  const float* bmg    = (const float*)d_in[10];
  const float* wrg    = (const float*)d_in[11];
  const float* brg    = (const float*)d_in[12];
  const float* whw    = (const float*)d_in[13];
  const float* bhw    = (const float*)d_in[14];
  const float* rmsw   = (const float*)d_in[15];
  const float* wpred  = (const float*)d_in[16];
  const float* bpred  = (const float*)d_in[17];

  char* ws = (char*)d_ws;
  size_t off = 0;
  auto carve = [&](size_t bytes) { char* p = ws + off; off += (bytes + 255) & ~(size_t)255; return p; };
  bf16_t* wpred_t  = (bf16_t*)carve(32000ull * 768 * 2);
  bf16_t* Wbig_t   = (bf16_t*)carve(3072ull * 1536 * 2);
  bf16_t* wc_t     = (bf16_t*)carve(768ull * 2304 * 2);
  bf16_t* wg1_t    = (bf16_t*)carve(768ull * 768 * 2);
  float*  bias_big = (float*) carve(3072 * 4);
  bf16_t* h_pad    = (bf16_t*)carve(2050ull * 768 * 2);
  bf16_t* hconv_bf = (bf16_t*)carve(2048ull * 768 * 2);
  bf16_t* currA_b  = (bf16_t*)carve(2048ull * 768 * 2);
  bf16_t* currB_b  = (bf16_t*)carve(2048ull * 768 * 2);
  bf16_t* tmp_bf   = (bf16_t*)carve(2048ull * 3072 * 2);

  hipMemsetAsync(Wbig_t + 2304ull * 1536, 0, 768ull * 1536 * 2, stream);
  // transposes: 64x64-tile vectorized. GRID = (n/64, fan_in/64).
  // wmv/wmg/wrg have fan_in = 1536 (comb = [left|right]) -> k-grid 24.
  transpose_cvt2<<<dim3(12, 24), 256, 0, stream>>>(wmv, Wbig_t,                        768, 1536);
  transpose_cvt2<<<dim3(12, 24), 256, 0, stream>>>(wmg, Wbig_t + 768ull * 1536,        768, 1536);
  transpose_cvt2<<<dim3(12, 24), 256, 0, stream>>>(wrg, Wbig_t + 1536ull * 1536,       768, 1536);
  transpose_cvt2<<<dim3(12, 12), 256, 0, stream>>>(whw, Wbig_t + 2304ull * 1536 + 768, 768, 1536);
  transpose_cvt2<<<dim3(12, 12), 256, 0, stream>>>(wg1, wg1_t, 768, 768);
  transpose_cvt2<<<dim3(500, 12), 256, 0, stream>>>(wpred, wpred_t, 32000, 768);
  build_wct<<<6912, 256, 0, stream>>>(conv_w, wc_t);
  build_bias<<<12, 256, 0, stream>>>(bmv, bmg, brg, bhw, bias_big);

  embed_k<<<2050, 256, 0, stream>>>(x, emb, pos, h_pad);

  // causal conv as shifted GEMM (K=2304, chunk shifts 0,1,2 into h_pad)
  gemm128<<<16 * 6, 256, 0, stream>>>(h_pad, 768, 2048, 16, 0, 1, 2,
                                      wc_t, 2304, conv_b, nullptr, 768, hconv_bf, nullptr);
  // curr0 = hconv * sigmoid(hconv @ wg1 + bg1)  (bf16-only state)
  gemm128<<<16 * 6, 256, 0, stream>>>(hconv_bf, 768, 2048, 16, 0, 0, 0,
                                      wg1_t, 768, bg1, nullptr, 768, currA_b, hconv_bf);

  bf16_t* curB = currA_b;
  bf16_t* nxtB = currB_b;
  for (int step = 1; step < 2048; step <<= 1) {
    const int M = 2048 - step;
    const int nRowT = (M + 127) / 128;
    // unified K=1536: chunk 0 = left (shift 0), chunk 1 = right (shift step)
    gemm128<<<nRowT * 24, 256, 0, stream>>>(
        curB, 768, M, nRowT, 0, step, 0, Wbig_t, 1536, bias_big,
        nullptr, 3072, tmp_bf, nullptr);
    merge_ew<<<2048, 256, 0, stream>>>(curB, nxtB, tmp_bf, rmsw, step);
    { bf16_t* tb_ = curB; curB = nxtB; nxtB = tb_; }
  }

  // logits = curr @ wpred + bpred  (NT full-line coalesced epilogue)
  gemm256<<<8 * 125, 512, 0, stream>>>(curB, 768, 2048, wpred_t, 768, 8, 125,
                                       bpred, (float*)d_out, 32000);
}